// Round 4
// baseline (1301.417 us; speedup 1.0000x reference)
//
#include <hip/hip_runtime.h>

// PairMixing: y_L[n,k,f] = sum_{triples (l1,l2,L)} (rbf[n,:]·W_t[f,:]) *
//                          sum_{i,j} cg_t[i,j,k] * x1_{l1}[n,i,f] * x2_{l2}[n,j,f]
// N=60000, F=128, B=32, 15 triples.
//
// v4b: identical strategy to v4 (bench infra failed; resubmission with
// defensive syntax only).
//   f-pair lanes + packed fp32 math: lane l owns features (2l, 2l+1); a
//   64-lane wave covers F=128 for one n. All x/y traffic is coalesced
//   dwordx2 (512 B per wave instruction); fma-class math is v_pk_fma_f32
//   (via __builtin_elementwise_fma on ext_vector float2) -> half the VALU
//   instruction stream of v3.
//   W pre-packed (prologue kernel, 245 KB in d_ws) as f-pair quads:
//   WTQ[t][q][l][b] = {W_t[2l][4q+b], W_t[2l+1][4q+b]}, b=0..3 -> coeff phase
//   reads two coalesced dwordx4 per (t,q), landing as register-paired f32x2.
//   Block 256 = 4 waves; wave w owns n = blk*8 + 2w .. +1; phase 2 is two
//   per-n passes (keeps VGPR low). cg reads wave-uniform -> s_load -> splat.

#define NPAIR 60000
#define NB    8
#define Y1OFF (NPAIR * 128)        // 7,680,000
#define Y2OFF (NPAIR * 128 * 4)    // 30,720,000
#define WT_BYTES (15 * 128 * 32 * 4)   // 245,760

typedef float f32x2 __attribute__((ext_vector_type(2)));
typedef float f32x4 __attribute__((ext_vector_type(4)));

__device__ __forceinline__ f32x2 pkfma(f32x2 a, f32x2 b, f32x2 c) {
#if defined(__has_builtin)
#if __has_builtin(__builtin_elementwise_fma)
    return __builtin_elementwise_fma(a, b, c);
#else
    f32x2 r; r.x = fmaf(a.x, b.x, c.x); r.y = fmaf(a.y, b.y, c.y); return r;
#endif
#else
    f32x2 r; r.x = fmaf(a.x, b.x, c.x); r.y = fmaf(a.y, b.y, c.y); return r;
#endif
}
__device__ __forceinline__ f32x2 bc(float s) { f32x2 r; r.x = s; r.y = s; return r; }
__device__ __forceinline__ f32x2 mk2(float a, float b) { f32x2 r; r.x = a; r.y = b; return r; }
__device__ __forceinline__ f32x2 ld2(const float* p) { return *(const f32x2*)p; }
__device__ __forceinline__ void st2(float* p, f32x2 v) { *(f32x2*)p = v; }

struct WPtrs { const float* w[15]; };

// WTQ f32x2-index: ((t*8+q)*64 + l)*4 + b  <=>  {W_t[2l][4q+b], W_t[2l+1][4q+b]}
__global__ void pack_W_kernel(WPtrs P, float* __restrict__ WT) {
    const int id = blockIdx.x * 256 + threadIdx.x;   // 0..7679 = 15*8*64
    if (id >= 15 * 8 * 64) return;
    const int t = id >> 9;
    const int q = (id >> 6) & 7;
    const int l = id & 63;
    const float* w = P.w[t];
    const f32x4 e = *(const f32x4*)(w + (size_t)(2 * l) * 32 + 4 * q);
    const f32x4 o = *(const f32x4*)(w + (size_t)(2 * l + 1) * 32 + 4 * q);
    f32x4* dst = (f32x4*)WT + (size_t)id * 2;
    f32x4 d0; d0.x = e.x; d0.y = o.x; d0.z = e.y; d0.w = o.y;
    f32x4 d1; d1.x = e.z; d1.y = o.z; d1.z = e.w; d1.w = o.w;
    dst[0] = d0;
    dst[1] = d1;
}

template<int D1, int D2, int DK>
__device__ __forceinline__ void triple_acc(
    const float* __restrict__ cg,
    const f32x2 (&a)[D1], const f32x2 (&b)[D2],
    f32x2 cf, f32x2 (&y)[DK])
{
    f32x2 tp[DK];
#pragma unroll
    for (int k = 0; k < DK; ++k) { tp[k].x = 0.f; tp[k].y = 0.f; }
#pragma unroll
    for (int i = 0; i < D1; ++i) {
#pragma unroll
        for (int j = 0; j < D2; ++j) {
            const f32x2 prod = a[i] * b[j];              // v_pk_mul_f32
#pragma unroll
            for (int k = 0; k < DK; ++k) {
                // cg[...] uniform address -> s_load; splat into packed fma
                tp[k] = pkfma(bc(cg[(i * D2 + j) * DK + k]), prod, tp[k]);
            }
        }
    }
#pragma unroll
    for (int k = 0; k < DK; ++k)
        y[k] = pkfma(cf, tp[k], y[k]);
}

template<bool USE_WT>
__global__ __launch_bounds__(256, 4) void pair_mixing_kernel(
    const float* __restrict__ x1_0, const float* __restrict__ x1_1, const float* __restrict__ x1_2,
    const float* __restrict__ x2_0, const float* __restrict__ x2_1, const float* __restrict__ x2_2,
    const float* __restrict__ rbf,
    const float* __restrict__ cg0,  const float* __restrict__ cg1,  const float* __restrict__ cg2,
    const float* __restrict__ cg3,  const float* __restrict__ cg4,  const float* __restrict__ cg5,
    const float* __restrict__ cg6,  const float* __restrict__ cg7,  const float* __restrict__ cg8,
    const float* __restrict__ cg9,  const float* __restrict__ cg10, const float* __restrict__ cg11,
    const float* __restrict__ cg12, const float* __restrict__ cg13, const float* __restrict__ cg14,
    const float* __restrict__ W0,  const float* __restrict__ W1,  const float* __restrict__ W2,
    const float* __restrict__ W3,  const float* __restrict__ W4,  const float* __restrict__ W5,
    const float* __restrict__ W6,  const float* __restrict__ W7,  const float* __restrict__ W8,
    const float* __restrict__ W9,  const float* __restrict__ W10, const float* __restrict__ W11,
    const float* __restrict__ W12, const float* __restrict__ W13, const float* __restrict__ W14,
    const float* __restrict__ WT,
    float* __restrict__ out)
{
    const int tid = threadIdx.x;
    const int l   = tid & 63;                 // lane
    const int wv  = tid >> 6;                 // wave 0..3
    const int f0  = l << 1;                   // this lane's f-pair base
    const int nb  = blockIdx.x * NB + wv * 2; // this wave's first n (wave-uniform)
    const int nbu = __builtin_amdgcn_readfirstlane(nb);
    const float* rbfp = rbf + ((size_t)nbu << 5);   // uniform base -> s_load path

    const float* Wt[15] = {W0, W1, W2, W3, W4, W5, W6, W7,
                           W8, W9, W10, W11, W12, W13, W14};

    // ---- phase 1: cf[t][nn] = rbf[nb+nn,:] . W_t[f-pair,:]  (f32x2 over f) ----
    f32x2 cf[15][2];
#pragma unroll
    for (int t = 0; t < 15; ++t) { cf[t][0] = bc(0.f); cf[t][1] = bc(0.f); }

#pragma unroll
    for (int q = 0; q < 8; ++q) {
        float rb[2][4];   // wave-uniform scalars (s_load)
#pragma unroll
        for (int nn = 0; nn < 2; ++nn)
#pragma unroll
            for (int r = 0; r < 4; ++r)
                rb[nn][r] = rbfp[nn * 32 + q * 4 + r];
#pragma unroll
        for (int t = 0; t < 15; ++t) {
            f32x2 wb[4];
            if (USE_WT) {
                const f32x4* wp = (const f32x4*)WT + (size_t)((t * 8 + q) * 64 + l) * 2;
                const f32x4 wA = wp[0];   // {W[2l][4q+0], W[2l+1][4q+0], W[2l][4q+1], W[2l+1][4q+1]}
                const f32x4 wB = wp[1];
                wb[0] = mk2(wA.x, wA.y); wb[1] = mk2(wA.z, wA.w);
                wb[2] = mk2(wB.x, wB.y); wb[3] = mk2(wB.z, wB.w);
            } else {
                const f32x4 e = *(const f32x4*)(Wt[t] + (size_t)f0 * 32 + 4 * q);
                const f32x4 o = *(const f32x4*)(Wt[t] + (size_t)(f0 + 1) * 32 + 4 * q);
                wb[0] = mk2(e.x, o.x);
                wb[1] = mk2(e.y, o.y);
                wb[2] = mk2(e.z, o.z);
                wb[3] = mk2(e.w, o.w);
            }
#pragma unroll
            for (int r = 0; r < 4; ++r) {
                cf[t][0] = pkfma(bc(rb[0][r]), wb[r], cf[t][0]);
                cf[t][1] = pkfma(bc(rb[1][r]), wb[r], cf[t][1]);
            }
        }
    }

    // ---- phase 2: tensor products, one pass per n ----
#pragma unroll
    for (int pass = 0; pass < 2; ++pass) {
        const int n = nb + pass;

        f32x2 a0[1], a1[3], a2[5], c0[1], c1[3], c2[5];
        a0[0] = ld2(x1_0 + (size_t)n * 128 + f0);
#pragma unroll
        for (int i = 0; i < 3; ++i) a1[i] = ld2(x1_1 + (size_t)(n * 3 + i) * 128 + f0);
#pragma unroll
        for (int i = 0; i < 5; ++i) a2[i] = ld2(x1_2 + (size_t)(n * 5 + i) * 128 + f0);
        c0[0] = ld2(x2_0 + (size_t)n * 128 + f0);
#pragma unroll
        for (int j = 0; j < 3; ++j) c1[j] = ld2(x2_1 + (size_t)(n * 3 + j) * 128 + f0);
#pragma unroll
        for (int j = 0; j < 5; ++j) c2[j] = ld2(x2_2 + (size_t)(n * 5 + j) * 128 + f0);

        f32x2 y0v[1], y1v[3], y2v[5];
#pragma unroll
        for (int k = 0; k < 1; ++k) y0v[k] = bc(0.f);
#pragma unroll
        for (int k = 0; k < 3; ++k) y1v[k] = bc(0.f);
#pragma unroll
        for (int k = 0; k < 5; ++k) y2v[k] = bc(0.f);

        triple_acc<1,1,1>(cg0,  a0, c0, cf[0][pass],  y0v);  // (0,0,0)
        triple_acc<1,3,3>(cg1,  a0, c1, cf[1][pass],  y1v);  // (0,1,1)
        triple_acc<1,5,5>(cg2,  a0, c2, cf[2][pass],  y2v);  // (0,2,2)
        triple_acc<3,1,3>(cg3,  a1, c0, cf[3][pass],  y1v);  // (1,0,1)
        triple_acc<3,3,1>(cg4,  a1, c1, cf[4][pass],  y0v);  // (1,1,0)
        triple_acc<3,3,3>(cg5,  a1, c1, cf[5][pass],  y1v);  // (1,1,1)
        triple_acc<3,3,5>(cg6,  a1, c1, cf[6][pass],  y2v);  // (1,1,2)
        triple_acc<3,5,3>(cg7,  a1, c2, cf[7][pass],  y1v);  // (1,2,1)
        triple_acc<3,5,5>(cg8,  a1, c2, cf[8][pass],  y2v);  // (1,2,2)
        triple_acc<5,1,5>(cg9,  a2, c0, cf[9][pass],  y2v);  // (2,0,2)
        triple_acc<5,3,3>(cg10, a2, c1, cf[10][pass], y1v);  // (2,1,1)
        triple_acc<5,3,5>(cg11, a2, c1, cf[11][pass], y2v);  // (2,1,2)
        triple_acc<5,5,1>(cg12, a2, c2, cf[12][pass], y0v);  // (2,2,0)
        triple_acc<5,5,3>(cg13, a2, c2, cf[13][pass], y1v);  // (2,2,1)
        triple_acc<5,5,5>(cg14, a2, c2, cf[14][pass], y2v);  // (2,2,2)

        st2(out + (size_t)n * 128 + f0, y0v[0]);
#pragma unroll
        for (int k = 0; k < 3; ++k)
            st2(out + (size_t)Y1OFF + (size_t)(n * 3 + k) * 128 + f0, y1v[k]);
#pragma unroll
        for (int k = 0; k < 5; ++k)
            st2(out + (size_t)Y2OFF + (size_t)(n * 5 + k) * 128 + f0, y2v[k]);
    }
}

extern "C" void kernel_launch(void* const* d_in, const int* in_sizes, int n_in,
                              void* d_out, int out_size, void* d_ws, size_t ws_size,
                              hipStream_t stream) {
    const float* x1_0 = (const float*)d_in[0];
    const float* x1_1 = (const float*)d_in[1];
    const float* x1_2 = (const float*)d_in[2];
    const float* x2_0 = (const float*)d_in[3];
    const float* x2_1 = (const float*)d_in[4];
    const float* x2_2 = (const float*)d_in[5];
    const float* rbf  = (const float*)d_in[6];
    // setup_inputs order: per triple, cg then W, interleaved
    const float* cg[15];
    const float* W[15];
    for (int t = 0; t < 15; ++t) {
        cg[t] = (const float*)d_in[7 + 2 * t];
        W[t]  = (const float*)d_in[8 + 2 * t];
    }
    float* out = (float*)d_out;

    const bool use_wt = (d_ws != nullptr) && (ws_size >= (size_t)WT_BYTES);

    dim3 grid(NPAIR / NB);   // 7500
    dim3 block(256);

    if (use_wt) {
        WPtrs P;
        for (int t = 0; t < 15; ++t) P.w[t] = W[t];
        pack_W_kernel<<<dim3(30), dim3(256), 0, stream>>>(P, (float*)d_ws);
        pair_mixing_kernel<true><<<grid, block, 0, stream>>>(
            x1_0, x1_1, x1_2, x2_0, x2_1, x2_2, rbf,
            cg[0], cg[1], cg[2], cg[3], cg[4], cg[5], cg[6], cg[7],
            cg[8], cg[9], cg[10], cg[11], cg[12], cg[13], cg[14],
            W[0], W[1], W[2], W[3], W[4], W[5], W[6], W[7],
            W[8], W[9], W[10], W[11], W[12], W[13], W[14],
            (const float*)d_ws, out);
    } else {
        pair_mixing_kernel<false><<<grid, block, 0, stream>>>(
            x1_0, x1_1, x1_2, x2_0, x2_1, x2_2, rbf,
            cg[0], cg[1], cg[2], cg[3], cg[4], cg[5], cg[6], cg[7],
            cg[8], cg[9], cg[10], cg[11], cg[12], cg[13], cg[14],
            W[0], W[1], W[2], W[3], W[4], W[5], W[6], W[7],
            W[8], W[9], W[10], W[11], W[12], W[13], W[14],
            nullptr, out);
    }
}